// Round 1
// baseline (755.961 us; speedup 1.0000x reference)
//
#include <hip/hip_runtime.h>

#define HID 30
#define TS  512
#define BPB 8   // batch elements per 256-thread block (32 lanes each)

__device__ __forceinline__ float sigm_f(float x) {
    // 1/(1+exp(-x)); saturates cleanly: exp->inf => rcp(inf)=0; exp->0 => 1
    return __builtin_amdgcn_rcpf(1.0f + __expf(-x));
}
__device__ __forceinline__ float tanh_f(float x) {
    // 1 - 2/(1+exp(2x)); x->+inf => 1, x->-inf => -1, no NaN
    return 1.0f - 2.0f * __builtin_amdgcn_rcpf(1.0f + __expf(2.0f * x));
}

__global__ __launch_bounds__(256, 2)
void lstm_fused_kernel(const float* __restrict__ batch,
                       const float* __restrict__ W_ih,
                       const float* __restrict__ W_hh,
                       const float* __restrict__ b_ih,
                       const float* __restrict__ b_hh,
                       const float* __restrict__ W_fc,
                       const float* __restrict__ b_fc,
                       float* __restrict__ out)
{
    __shared__ float xs[BPB * TS];   // 16 KB: x for this block's 8 batch rows

    const int tid = threadIdx.x;
    const int grp = tid >> 5;          // local batch index 0..7
    const int j   = tid & 31;          // hidden-unit lane, 0..29 active
    const int b   = blockIdx.x * BPB + grp;

    // ---- stage x (fully coalesced; rows are contiguous: [B,T,1]) ----
    const float* src = batch + (size_t)blockIdx.x * (BPB * TS);
    #pragma unroll
    for (int i = 0; i < (BPB * TS) / 256; ++i)
        xs[tid + i * 256] = src[tid + i * 256];

    // ---- per-lane weights into VGPRs (one-time) ----
    const int jj = (j < HID) ? j : (HID - 1);   // lanes 30/31 mirror lane 29
    float wi[HID], wf[HID], wg[HID], wo[HID];
    #pragma unroll
    for (int k = 0; k < HID; ++k) {
        wi[k] = W_hh[(jj          ) * HID + k];
        wf[k] = W_hh[(jj +     HID) * HID + k];
        wg[k] = W_hh[(jj + 2 * HID) * HID + k];
        wo[k] = W_hh[(jj + 3 * HID) * HID + k];
    }
    const float bi = b_ih[jj          ] + b_hh[jj          ];
    const float bf = b_ih[jj +     HID] + b_hh[jj +     HID];
    const float bg = b_ih[jj + 2 * HID] + b_hh[jj + 2 * HID];
    const float bo = b_ih[jj + 3 * HID] + b_hh[jj + 3 * HID];
    const float xi = W_ih[jj          ];
    const float xf = W_ih[jj +     HID];
    const float xg = W_ih[jj + 2 * HID];
    const float xo = W_ih[jj + 3 * HID];

    __syncthreads();

    // ---- recurrence ----
    float h[HID];
    #pragma unroll
    for (int k = 0; k < HID; ++k) h[k] = 0.0f;
    float c = 0.0f;

    const int base4 = (tid & 32) << 2;   // bpermute byte base: my wave-half

    for (int t = 0; t < TS; ++t) {
        const float x = xs[grp * TS + t];      // uniform per 32-lane group
        float ai = fmaf(x, xi, bi);
        float af = fmaf(x, xf, bf);
        float ag = fmaf(x, xg, bg);
        float ao = fmaf(x, xo, bo);
        #pragma unroll
        for (int k = 0; k < HID; ++k) {
            ai = fmaf(h[k], wi[k], ai);
            af = fmaf(h[k], wf[k], af);
            ag = fmaf(h[k], wg[k], ag);
            ao = fmaf(h[k], wo[k], ao);
        }
        const float ig = sigm_f(ai);
        const float fg = sigm_f(af);
        const float gg = tanh_f(ag);
        const float og = sigm_f(ao);
        c = fmaf(fg, c, ig * gg);
        const float hown = og * tanh_f(c);

        // broadcast h_own of lanes 0..29 (within this 32-lane group) to all
        const int hbits = __float_as_int(hown);
        #pragma unroll
        for (int k = 0; k < HID; ++k)
            h[k] = __int_as_float(
                __builtin_amdgcn_ds_bpermute(base4 | (k << 2), hbits));
    }

    // ---- final projection: out[b] = b_fc + sum_k h[k]*W_fc[k] ----
    if (j == 0) {
        float acc = b_fc[0];
        #pragma unroll
        for (int k = 0; k < HID; ++k) acc = fmaf(h[k], W_fc[k], acc);
        out[b] = acc;
    }
}

extern "C" void kernel_launch(void* const* d_in, const int* in_sizes, int n_in,
                              void* d_out, int out_size, void* d_ws, size_t ws_size,
                              hipStream_t stream) {
    const float* batch = (const float*)d_in[0];
    const float* W_ih  = (const float*)d_in[1];
    const float* W_hh  = (const float*)d_in[2];
    const float* b_ih  = (const float*)d_in[3];
    const float* b_hh  = (const float*)d_in[4];
    const float* W_fc  = (const float*)d_in[5];
    const float* b_fc  = (const float*)d_in[6];
    float* out = (float*)d_out;

    const int blocks = (8192 + BPB - 1) / BPB;   // 1024
    lstm_fused_kernel<<<blocks, 256, 0, stream>>>(batch, W_ih, W_hh, b_ih, b_hh,
                                                  W_fc, b_fc, out);
}

// Round 2
// 558.016 us; speedup vs baseline: 1.3547x; 1.3547x over previous
//
#include <hip/hip_runtime.h>

#define HID 30
#define TS  512
#define WPB 4   // waves (= batch elements) per 256-thread block
#define LOG2E 1.44269504088896340736f

__global__ __launch_bounds__(256, 4)
void lstm_kernel(const float* __restrict__ batch,
                 const float* __restrict__ W_ih,
                 const float* __restrict__ W_hh,
                 const float* __restrict__ b_ih,
                 const float* __restrict__ b_hh,
                 const float* __restrict__ W_fc,
                 const float* __restrict__ b_fc,
                 float* __restrict__ out)
{
    __shared__ float xs[WPB][TS];   // 8 KB: x rows, one per wave
    __shared__ float hs[WPB][32];   // h state per wave (slots 30,31 unused-dup)

    const int tid  = threadIdx.x;
    const int w    = tid >> 6;          // wave id in block
    const int lane = tid & 63;
    const int half = lane >> 5;         // 0: gates i,f   1: gates g,o
    const int j    = lane & 31;         // hidden unit (j<30 active)
    const int jj   = (j < HID) ? j : (HID - 1);
    const int b    = blockIdx.x * WPB + w;

    // ---- per-wave x staging (coalesced, no cross-wave sharing -> no barrier)
    const float* src = batch + (size_t)b * TS;
    #pragma unroll
    for (int i = 0; i < TS / 64; ++i)
        xs[w][lane + i * 64] = src[lane + i * 64];

    // ---- init h = 0 (both halves write same value to same slot: benign)
    hs[w][j] = 0.0f;

    // ---- per-lane weights: row0 = gate i (half0) or g (half1); row1 = f or o
    const int row0 = jj + (half ? 2 * HID : 0);
    const int row1 = row0 + HID;
    float w0[HID], w1[HID];
    #pragma unroll
    for (int k = 0; k < HID; ++k) {
        w0[k] = W_hh[row0 * HID + k];
        w1[k] = W_hh[row1 * HID + k];
    }
    const float bb0 = b_ih[row0] + b_hh[row0];
    const float bb1 = b_ih[row1] + b_hh[row1];
    const float xw0 = W_ih[row0];
    const float xw1 = W_ih[row1];

    // activation merge: act0 = half ? tanh(a0) : sigm(a0)
    //   sigm(z) = rcp(1 + exp2(-z*log2e));  tanh(z) = 2*sigm(2z) - 1
    //   act0 = fma(rcp(1 + exp2(a0*nm0)), m0, ad0)
    const float m0  = half ? 2.0f : 1.0f;
    const float ad0 = half ? -1.0f : 0.0f;
    const float nm0 = -m0 * LOG2E;
    const int swap4 = (lane ^ 32) << 2;   // bpermute partner (other half)

    float c = 0.0f;

    for (int t = 0; t < TS; ++t) {
        const float x = xs[w][t];                       // uniform -> broadcast
        float a0 = fmaf(x, xw0, bb0);
        float a1 = fmaf(x, xw1, bb1);
        // h dot products: 8x ds_read_b128 (uniform addr -> broadcast), 60 FMA
        #pragma unroll
        for (int kb = 0; kb < 8; ++kb) {
            const float4 hv = *(const float4*)&hs[w][kb * 4];
            const int k0 = kb * 4;
            if (k0 + 0 < HID) { a0 = fmaf(hv.x, w0[k0+0], a0); a1 = fmaf(hv.x, w1[k0+0], a1); }
            if (k0 + 1 < HID) { a0 = fmaf(hv.y, w0[k0+1], a0); a1 = fmaf(hv.y, w1[k0+1], a1); }
            if (k0 + 2 < HID) { a0 = fmaf(hv.z, w0[k0+2], a0); a1 = fmaf(hv.z, w1[k0+2], a1); }
            if (k0 + 3 < HID) { a0 = fmaf(hv.w, w0[k0+3], a0); a1 = fmaf(hv.w, w1[k0+3], a1); }
        }
        const float s0   = __builtin_amdgcn_rcpf(1.0f + exp2f(a0 * nm0));
        const float act0 = fmaf(s0, m0, ad0);                        // i or g
        const float act1 = __builtin_amdgcn_rcpf(1.0f + exp2f(a1 * (-LOG2E))); // f or o
        // exchange with partner half
        const float r0 = __int_as_float(__builtin_amdgcn_ds_bpermute(swap4, __float_as_int(act0)));
        const float r1 = __int_as_float(__builtin_amdgcn_ds_bpermute(swap4, __float_as_int(act1)));
        const float iv = half ? r0 : act0;
        const float fv = half ? r1 : act1;
        const float gv = half ? act0 : r0;
        const float ov = half ? act1 : r1;
        c = fmaf(fv, c, iv * gv);
        const float th = fmaf(-2.0f,
            __builtin_amdgcn_rcpf(1.0f + exp2f(c * (2.0f * LOG2E))), 1.0f);
        hs[w][j] = ov * th;   // both halves write identical value
    }

    // ---- final projection: out[b] = b_fc + h . W_fc (all lanes redundant)
    float acc = b_fc[0];
    #pragma unroll
    for (int k = 0; k < HID; ++k)
        acc = fmaf(hs[w][k], W_fc[k], acc);
    if (lane == 0) out[b] = acc;
}

extern "C" void kernel_launch(void* const* d_in, const int* in_sizes, int n_in,
                              void* d_out, int out_size, void* d_ws, size_t ws_size,
                              hipStream_t stream) {
    const float* batch = (const float*)d_in[0];
    const float* W_ih  = (const float*)d_in[1];
    const float* W_hh  = (const float*)d_in[2];
    const float* b_ih  = (const float*)d_in[3];
    const float* b_hh  = (const float*)d_in[4];
    const float* W_fc  = (const float*)d_in[5];
    const float* b_fc  = (const float*)d_in[6];
    float* out = (float*)d_out;

    const int blocks = 8192 / WPB;   // 2048
    lstm_kernel<<<blocks, 256, 0, stream>>>(batch, W_ih, W_hh, b_ih, b_hh,
                                            W_fc, b_fc, out);
}